// Round 2
// baseline (25973.541 us; speedup 1.0000x reference)
//
#include <hip/hip_runtime.h>
#include <stdint.h>

typedef _Float16 f16;
typedef _Float16 f16x8 __attribute__((ext_vector_type(8)));
typedef float f32x4 __attribute__((ext_vector_type(4)));

#define T_STEPS 512
#define NBATCH 64
#define CH 64          // chunk length (timesteps per pipeline chunk)
#define NCH 8          // number of chunks

__device__ __forceinline__ float sigmoidf_(float x) {
    return 1.0f / (1.0f + __expf(-x));
}
__device__ __forceinline__ float tanh_(float x) {
    x = fminf(fmaxf(x, -15.0f), 15.0f);
    float e = __expf(2.0f * x);
    return (e - 1.0f) / (e + 1.0f);
}

// ---------------- fold LoRA into dense weight: dst = fp16(W + 2*B@A) --------
// W: [4096][K] f32, Bm: [4096][8] f32, Am: [8][K] f32, dst: [4096][K] f16
__global__ __launch_bounds__(256) void fold_lora(
    const float* __restrict__ W, const float* __restrict__ Bm,
    const float* __restrict__ Am, f16* __restrict__ dst, int K) {
    int cid = blockIdx.x * 256 + threadIdx.x;
    int kc = K >> 3;
    int r = cid / kc;
    int k0 = (cid - r * kc) * 8;
    float bb[8];
#pragma unroll
    for (int j = 0; j < 8; j++) bb[j] = Bm[r * 8 + j];
#pragma unroll
    for (int i = 0; i < 8; i++) {
        float s = 0.0f;
#pragma unroll
        for (int j = 0; j < 8; j++) s += bb[j] * Am[j * K + k0 + i];
        float v = W[(size_t)r * K + k0 + i] + 2.0f * s;
        dst[(size_t)r * K + k0 + i] = (f16)v;
    }
}

// ---------------- bias sums + flag/cstate zeroing ----------------------------
// grid 256 x 256 = 65536 threads
__global__ __launch_bounds__(256) void init_misc(
    const float* __restrict__ bih0, const float* __restrict__ bhh0,
    const float* __restrict__ bih1, const float* __restrict__ bhh1,
    float* __restrict__ bsum0, float* __restrict__ bsum1,
    int* __restrict__ flags0, int* __restrict__ flags1,
    float* __restrict__ c0, float* __restrict__ c1) {
    int i = blockIdx.x * 256 + threadIdx.x;
    if (i < 4096) {
        bsum0[i] = bih0[i] + bhh0[i];
        bsum1[i] = bih1[i] + bhh1[i];
    }
    if (i < 256) { flags0[i] = 0; flags1[i] = 0; }
    c0[i] = 0.0f;
    c1[i] = 0.0f;
}

// ---------------- embedding gather chunk -> fp16 seqc [CH][B][512] -----------
__global__ __launch_bounds__(256) void embed_gather(
    const int* __restrict__ x, const float* __restrict__ emb,
    f16* __restrict__ seqc, int t0) {
    int lt = blockIdx.x;           // [0,CH)
    int t = t0 + lt;
#pragma unroll
    for (int c = 0; c < 16; c++) {
        int lin = c * 256 + threadIdx.x;   // [0,4096)
        int b = lin >> 6;                  // [0,64)
        int e0 = (lin & 63) * 8;           // [0,512)
        int tok = x[b * 512 + t];          // x is [B][T]
        const float* src = emb + (size_t)tok * 512 + e0;
        f16x8 v;
#pragma unroll
        for (int i = 0; i < 8; i++) v[i] = (f16)src[i];
        *(f16x8*)&seqc[((size_t)lt * 64 + b) * 512 + e0] = v;
    }
}

// ---------------- NT GEMM: C[4096][4096] f32 = A[4096][K] f16 @ Bw[4096][K]^T
// tile 128x128, block 256 threads, grid 1024 (32 x 32 tiles)
__global__ __launch_bounds__(256) void gemm_nt(
    const f16* __restrict__ A, const f16* __restrict__ Bw,
    float* __restrict__ C, int K) {
    __shared__ f16 As[128 * 40];  // pad 32->40 halves to break bank conflicts
    __shared__ f16 Bs[128 * 40];
    int bid = blockIdx.x;
    int mt = bid & 31, nt = bid >> 5;
    int tid = threadIdx.x;
    int w = tid >> 6, lane = tid & 63;
    int lm = lane & 15, lq = lane >> 4;
    int wm = (w >> 1) * 64, wn = (w & 1) * 64;
    f32x4 acc[4][4];
#pragma unroll
    for (int i = 0; i < 4; i++)
#pragma unroll
        for (int j = 0; j < 4; j++) acc[i][j] = f32x4{0.f, 0.f, 0.f, 0.f};
    const f16* Ab = A + (size_t)mt * 128 * K;
    const f16* Bb = Bw + (size_t)nt * 128 * K;
    int nkc = K >> 5;
    for (int kc = 0; kc < nkc; kc++) {
#pragma unroll
        for (int i = 0; i < 2; i++) {
            int cid = tid + i * 256;          // [0,512)
            int r = cid >> 2, c8 = (cid & 3) * 8;
            *(f16x8*)&As[r * 40 + c8] = *(const f16x8*)&Ab[(size_t)r * K + kc * 32 + c8];
            *(f16x8*)&Bs[r * 40 + c8] = *(const f16x8*)&Bb[(size_t)r * K + kc * 32 + c8];
        }
        __syncthreads();
        f16x8 af[4], bf[4];
#pragma unroll
        for (int mi = 0; mi < 4; mi++)
            af[mi] = *(const f16x8*)&As[(wm + mi * 16 + lm) * 40 + lq * 8];
#pragma unroll
        for (int ni = 0; ni < 4; ni++)
            bf[ni] = *(const f16x8*)&Bs[(wn + ni * 16 + lm) * 40 + lq * 8];
#pragma unroll
        for (int mi = 0; mi < 4; mi++)
#pragma unroll
            for (int ni = 0; ni < 4; ni++)
                acc[mi][ni] = __builtin_amdgcn_mfma_f32_16x16x32_f16(
                    af[mi], bf[ni], acc[mi][ni], 0, 0, 0);
        __syncthreads();
    }
#pragma unroll
    for (int mi = 0; mi < 4; mi++)
#pragma unroll
        for (int ni = 0; ni < 4; ni++)
#pragma unroll
            for (int r = 0; r < 4; r++) {
                int m = mt * 128 + wm + mi * 16 + lq * 4 + r;
                int n = nt * 128 + wn + ni * 16 + lm;
                C[(size_t)m * 4096 + n] = acc[mi][ni][r];
            }
}

// ---------------- persistent LSTM recurrence over one chunk ------------------
// grid 256 = 4 batch-groups x 64 j-groups. Block owns 16 batches x 16 hid.
// W_hh_eff rows (16 hid x 4 gates = 64 rows) live in registers as B-fragments.
// hexch: exchange buffer with (smask+1) slots of [64][1024] f16; slot = t & smask.
__global__ __launch_bounds__(256, 2) void lstm_recur(
    const float* __restrict__ xp,     // [CH*64][4096] f32 (chunk-local)
    const f16* __restrict__ Wh,       // [4096][1024] f16 (folded)
    const float* __restrict__ bsum,   // [4096] = b_ih + b_hh
    f16* __restrict__ hexch,          // [(smask+1)][64][1024] f16
    int* __restrict__ flags,          // [256], monotone absolute t
    float* __restrict__ cstate,       // [64][1024] f32 persistent c
    int t0, int smask,
    const int* __restrict__ lengths,  // [64] or null
    float* __restrict__ dout) {       // [64][1024] f32 or null
    __shared__ f16 hbuf[16 * 1032];   // h_prev slice, padded stride
    __shared__ float xch[4 * 16 * 16];// cross-wave gate exchange
    int tid = threadIdx.x;
    int g = tid >> 6, lane = tid & 63;
    int lm = lane & 15, lq = lane >> 4;
    int bid = blockIdx.x;
    int bg = bid >> 6, jg = bid & 63;

    // ---- load W fragments into registers (stay resident all CH steps) ----
    f16x8 wfrag[32];
    {
        int grow = g * 1024 + jg * 16 + lm;     // global gate row
        const f16* wp = Wh + (size_t)grow * 1024 + lq * 8;
#pragma unroll
        for (int kk = 0; kk < 32; kk++) wfrag[kk] = *(const f16x8*)(wp + kk * 32);
    }
    int eb = tid >> 4, eu = tid & 15;
    int batch = bg * 16 + eb;
    int hidx = jg * 16 + eu;
    float bias[4];
#pragma unroll
    for (int g2 = 0; g2 < 4; g2++) bias[g2] = bsum[g2 * 1024 + hidx];
    int mylen = (lengths != nullptr) ? lengths[batch] : -1;
    float c = (t0 > 0) ? cstate[(size_t)batch * 1024 + hidx] : 0.0f;
    const int myflag = bg * 64 + jg;

    for (int lt = 0; lt < CH; lt++) {
        int t = t0 + lt;
        f32x4 pre = f32x4{0.f, 0.f, 0.f, 0.f};
        if (t > 0) {
            // wait for all 64 blocks of my batch-group to have written h_{t-1}
            if (tid < 64) {
                const int* fl = flags + bg * 64;
                for (;;) {
                    int v = __hip_atomic_load(fl + tid, __ATOMIC_RELAXED,
                                              __HIP_MEMORY_SCOPE_AGENT);
                    if (__all(v >= t)) break;
                    __builtin_amdgcn_s_sleep(1);
                }
            }
            __syncthreads();
            __threadfence();  // acquire: invalidate caches before reading h
            const f16* hprev = hexch + (size_t)((t - 1) & smask) * (NBATCH * 1024);
#pragma unroll
            for (int i = 0; i < 8; i++) {
                int lin = tid + i * 256;          // [0,2048) 16B-chunks
                int b = lin >> 7, k0 = (lin & 127) * 8;
                *(f16x8*)&hbuf[b * 1032 + k0] =
                    *(const f16x8*)&hprev[(size_t)(bg * 16 + b) * 1024 + k0];
            }
            __syncthreads();
            f32x4 a0 = f32x4{0.f,0.f,0.f,0.f}, a1 = f32x4{0.f,0.f,0.f,0.f};
            f32x4 a2 = f32x4{0.f,0.f,0.f,0.f}, a3 = f32x4{0.f,0.f,0.f,0.f};
            const f16* hb = &hbuf[lm * 1032 + lq * 8];
#pragma unroll
            for (int kk = 0; kk < 32; kk += 4) {
                a0 = __builtin_amdgcn_mfma_f32_16x16x32_f16(*(const f16x8*)(hb + (kk + 0) * 32), wfrag[kk + 0], a0, 0, 0, 0);
                a1 = __builtin_amdgcn_mfma_f32_16x16x32_f16(*(const f16x8*)(hb + (kk + 1) * 32), wfrag[kk + 1], a1, 0, 0, 0);
                a2 = __builtin_amdgcn_mfma_f32_16x16x32_f16(*(const f16x8*)(hb + (kk + 2) * 32), wfrag[kk + 2], a2, 0, 0, 0);
                a3 = __builtin_amdgcn_mfma_f32_16x16x32_f16(*(const f16x8*)(hb + (kk + 3) * 32), wfrag[kk + 3], a3, 0, 0, 0);
            }
            pre = (a0 + a1) + (a2 + a3);
        }
        // cross-wave exchange: D element (m=lq*4+r = batch, n=lm = unit) of gate g
#pragma unroll
        for (int r = 0; r < 4; r++)
            xch[(g * 16 + lq * 4 + r) * 16 + lm] = pre[r];
        __syncthreads();
        float pg[4];
        const float* xprow = xp + ((size_t)lt * 64 + batch) * 4096 + hidx;
#pragma unroll
        for (int g2 = 0; g2 < 4; g2++)
            pg[g2] = xch[(g2 * 16 + eb) * 16 + eu] + xprow[g2 * 1024] + bias[g2];
        float iv = sigmoidf_(pg[0]);
        float fv = sigmoidf_(pg[1]);
        float gv = tanh_(pg[2]);
        float ov = sigmoidf_(pg[3]);
        c = fv * c + iv * gv;
        float h = ov * tanh_(c);
        hexch[(size_t)(t & smask) * (NBATCH * 1024) + (size_t)batch * 1024 + hidx] = (f16)h;
        if (dout != nullptr && t == mylen - 1)
            dout[(size_t)batch * 1024 + hidx] = h;
        __syncthreads();  // all waves' h stores complete before flag release
        if (tid == 0)
            __hip_atomic_store(flags + myflag, t + 1, __ATOMIC_RELEASE,
                               __HIP_MEMORY_SCOPE_AGENT);
    }
    cstate[(size_t)batch * 1024 + hidx] = c;
}

extern "C" void kernel_launch(void* const* d_in, const int* in_sizes, int n_in,
                              void* d_out, int out_size, void* d_ws, size_t ws_size,
                              hipStream_t stream) {
    const int*   x     = (const int*)d_in[0];
    const int*   len   = (const int*)d_in[1];
    const float* emb   = (const float*)d_in[2];
    const float* W_ih0 = (const float*)d_in[3];
    const float* b_ih0 = (const float*)d_in[4];
    const float* A_ih0 = (const float*)d_in[5];
    const float* B_ih0 = (const float*)d_in[6];
    const float* W_hh0 = (const float*)d_in[7];
    const float* b_hh0 = (const float*)d_in[8];
    const float* A_hh0 = (const float*)d_in[9];
    const float* B_hh0 = (const float*)d_in[10];
    const float* W_ih1 = (const float*)d_in[11];
    const float* b_ih1 = (const float*)d_in[12];
    const float* A_ih1 = (const float*)d_in[13];
    const float* B_ih1 = (const float*)d_in[14];
    const float* W_hh1 = (const float*)d_in[15];
    const float* b_hh1 = (const float*)d_in[16];
    const float* A_hh1 = (const float*)d_in[17];
    const float* B_hh1 = (const float*)d_in[18];

    char* ws = (char*)d_ws;
    size_t off = 0;
    auto alloc = [&](size_t bytes) {
        size_t o = off;
        off += (bytes + 255) & ~(size_t)255;
        return o;
    };
    // total ~105 MB
    f16*   W0f    = (f16*)(ws + alloc((size_t)4096 * 512 * 2));    //  4 MB
    f16*   Wh0f   = (f16*)(ws + alloc((size_t)4096 * 1024 * 2));   //  8 MB
    f16*   W1f    = (f16*)(ws + alloc((size_t)4096 * 1024 * 2));   //  8 MB
    f16*   Wh1f   = (f16*)(ws + alloc((size_t)4096 * 1024 * 2));   //  8 MB
    float* bsum0  = (float*)(ws + alloc(4096 * 4));
    float* bsum1  = (float*)(ws + alloc(4096 * 4));
    int*   flags0 = (int*)(ws + alloc(4096));
    int*   flags1 = (int*)(ws + alloc(4096));
    float* c0st   = (float*)(ws + alloc((size_t)64 * 1024 * 4));   // 256 KB
    float* c1st   = (float*)(ws + alloc((size_t)64 * 1024 * 4));   // 256 KB
    f16*   hx1    = (f16*)(ws + alloc((size_t)2 * 64 * 1024 * 2)); // 256 KB
    f16*   seqc   = (f16*)(ws + alloc((size_t)CH * 64 * 512 * 2)); //  4 MB
    f16*   h0c    = (f16*)(ws + alloc((size_t)CH * 64 * 1024 * 2));//  8 MB
    float* xpc    = (float*)(ws + alloc((size_t)CH * 64 * 4096 * 4)); // 64 MB
    (void)ws_size; (void)in_sizes; (void)n_in; (void)out_size;

    // Phase A: fold LoRA, biases, flags, c states
    fold_lora<<<1024, 256, 0, stream>>>(W_ih0, B_ih0, A_ih0, W0f, 512);
    fold_lora<<<2048, 256, 0, stream>>>(W_hh0, B_hh0, A_hh0, Wh0f, 1024);
    fold_lora<<<2048, 256, 0, stream>>>(W_ih1, B_ih1, A_ih1, W1f, 1024);
    fold_lora<<<2048, 256, 0, stream>>>(W_hh1, B_hh1, A_hh1, Wh1f, 1024);
    init_misc<<<256, 256, 0, stream>>>(b_ih0, b_hh0, b_ih1, b_hh1,
                                       bsum0, bsum1, flags0, flags1, c0st, c1st);

    // Chunked pipeline: embed -> gemm0 -> recur0 -> gemm1 -> recur1
    for (int cix = 0; cix < NCH; cix++) {
        int t0 = cix * CH;
        embed_gather<<<CH, 256, 0, stream>>>(x, emb, seqc, t0);
        gemm_nt<<<1024, 256, 0, stream>>>(seqc, W0f, xpc, 512);
        lstm_recur<<<256, 256, 0, stream>>>(xpc, Wh0f, bsum0, h0c, flags0,
                                            c0st, t0, CH - 1, nullptr, nullptr);
        gemm_nt<<<1024, 256, 0, stream>>>(h0c, W1f, xpc, 1024);
        lstm_recur<<<256, 256, 0, stream>>>(xpc, Wh1f, bsum1, hx1, flags1,
                                            c1st, t0, 1, len, (float*)d_out);
    }
}

// Round 3
// 8343.179 us; speedup vs baseline: 3.1131x; 3.1131x over previous
//
#include <hip/hip_runtime.h>
#include <stdint.h>

typedef _Float16 f16;
typedef _Float16 f16x8 __attribute__((ext_vector_type(8)));
typedef float f32x4 __attribute__((ext_vector_type(4)));

#define T_STEPS 512
#define NBATCH 64
#define CH 64          // chunk length (timesteps per pipeline chunk)
#define NCH 8          // number of chunks

__device__ __forceinline__ float sigmoidf_(float x) {
    return 1.0f / (1.0f + __expf(-x));
}
__device__ __forceinline__ float tanh_(float x) {
    x = fminf(fmaxf(x, -15.0f), 15.0f);
    float e = __expf(2.0f * x);
    return (e - 1.0f) / (e + 1.0f);
}

// ---------------- fold LoRA into dense weight: dst = fp16(W + 2*B@A) --------
__global__ __launch_bounds__(256) void fold_lora(
    const float* __restrict__ W, const float* __restrict__ Bm,
    const float* __restrict__ Am, f16* __restrict__ dst, int K) {
    int cid = blockIdx.x * 256 + threadIdx.x;
    int kc = K >> 3;
    int r = cid / kc;
    int k0 = (cid - r * kc) * 8;
    float bb[8];
#pragma unroll
    for (int j = 0; j < 8; j++) bb[j] = Bm[r * 8 + j];
#pragma unroll
    for (int i = 0; i < 8; i++) {
        float s = 0.0f;
#pragma unroll
        for (int j = 0; j < 8; j++) s += bb[j] * Am[j * K + k0 + i];
        float v = W[(size_t)r * K + k0 + i] + 2.0f * s;
        dst[(size_t)r * K + k0 + i] = (f16)v;
    }
}

// ---------------- bias sums + flag/cstate zeroing ----------------------------
__global__ __launch_bounds__(256) void init_misc(
    const float* __restrict__ bih0, const float* __restrict__ bhh0,
    const float* __restrict__ bih1, const float* __restrict__ bhh1,
    float* __restrict__ bsum0, float* __restrict__ bsum1,
    int* __restrict__ flags0, int* __restrict__ flags1,
    float* __restrict__ c0, float* __restrict__ c1) {
    int i = blockIdx.x * 256 + threadIdx.x;
    if (i < 4096) {
        bsum0[i] = bih0[i] + bhh0[i];
        bsum1[i] = bih1[i] + bhh1[i];
    }
    if (i < 256) { flags0[i] = 0; flags1[i] = 0; }
    c0[i] = 0.0f;
    c1[i] = 0.0f;
}

// ---------------- embedding gather chunk -> fp16 seqc [CH][B][512] -----------
__global__ __launch_bounds__(256) void embed_gather(
    const int* __restrict__ x, const float* __restrict__ emb,
    f16* __restrict__ seqc, int t0) {
    int lt = blockIdx.x;
    int t = t0 + lt;
#pragma unroll
    for (int c = 0; c < 16; c++) {
        int lin = c * 256 + threadIdx.x;
        int b = lin >> 6;
        int e0 = (lin & 63) * 8;
        int tok = x[b * 512 + t];
        const float* src = emb + (size_t)tok * 512 + e0;
        f16x8 v;
#pragma unroll
        for (int i = 0; i < 8; i++) v[i] = (f16)src[i];
        *(f16x8*)&seqc[((size_t)lt * 64 + b) * 512 + e0] = v;
    }
}

// ---------------- NT GEMM: C = A[4096][K] @ Bw[4096][K]^T --------------------
// C stored gate-interleaved: C[m][u*4+gate] where n = gate*1024+u.
// tile 128x128, block 256 threads, grid 1024 (32 x 32 tiles)
__global__ __launch_bounds__(256) void gemm_nt(
    const f16* __restrict__ A, const f16* __restrict__ Bw,
    float* __restrict__ C, int K) {
    __shared__ f16 As[128 * 40];
    __shared__ f16 Bs[128 * 40];
    int bid = blockIdx.x;
    int mt = bid & 31, nt = bid >> 5;
    int tid = threadIdx.x;
    int w = tid >> 6, lane = tid & 63;
    int lm = lane & 15, lq = lane >> 4;
    int wm = (w >> 1) * 64, wn = (w & 1) * 64;
    f32x4 acc[4][4];
#pragma unroll
    for (int i = 0; i < 4; i++)
#pragma unroll
        for (int j = 0; j < 4; j++) acc[i][j] = f32x4{0.f, 0.f, 0.f, 0.f};
    const f16* Ab = A + (size_t)mt * 128 * K;
    const f16* Bb = Bw + (size_t)nt * 128 * K;
    int nkc = K >> 5;
    for (int kc = 0; kc < nkc; kc++) {
#pragma unroll
        for (int i = 0; i < 2; i++) {
            int cid = tid + i * 256;
            int r = cid >> 2, c8 = (cid & 3) * 8;
            *(f16x8*)&As[r * 40 + c8] = *(const f16x8*)&Ab[(size_t)r * K + kc * 32 + c8];
            *(f16x8*)&Bs[r * 40 + c8] = *(const f16x8*)&Bb[(size_t)r * K + kc * 32 + c8];
        }
        __syncthreads();
        f16x8 af[4], bf[4];
#pragma unroll
        for (int mi = 0; mi < 4; mi++)
            af[mi] = *(const f16x8*)&As[(wm + mi * 16 + lm) * 40 + lq * 8];
#pragma unroll
        for (int ni = 0; ni < 4; ni++)
            bf[ni] = *(const f16x8*)&Bs[(wn + ni * 16 + lm) * 40 + lq * 8];
#pragma unroll
        for (int mi = 0; mi < 4; mi++)
#pragma unroll
            for (int ni = 0; ni < 4; ni++)
                acc[mi][ni] = __builtin_amdgcn_mfma_f32_16x16x32_f16(
                    af[mi], bf[ni], acc[mi][ni], 0, 0, 0);
        __syncthreads();
    }
#pragma unroll
    for (int mi = 0; mi < 4; mi++)
#pragma unroll
        for (int ni = 0; ni < 4; ni++)
#pragma unroll
            for (int r = 0; r < 4; r++) {
                int m = mt * 128 + wm + mi * 16 + lq * 4 + r;
                int n = nt * 128 + wn + ni * 16 + lm;
                int gate = n >> 10, u = n & 1023;
                C[(size_t)m * 4096 + u * 4 + gate] = acc[mi][ni][r];
            }
}

// ---------------- persistent LSTM recurrence over one chunk ------------------
// grid 256 = 4 batch-groups x 64 j-groups. Block owns 16 batches x 16 hid.
// Fence-free cross-block exchange: h and flags move via relaxed agent-scope
// atomics (device-coherent at the MALL), ordered by the vmcnt(0) drain that
// __syncthreads performs. No __threadfence -> no per-step L2 wb/inv.
__global__ __launch_bounds__(256, 2) void lstm_recur(
    const float* __restrict__ xp,     // [CH*64][4096] f32, gate-interleaved
    const f16* __restrict__ Wh,       // [4096][1024] f16 (folded)
    const float* __restrict__ bsum,   // [4096] = b_ih + b_hh (gate-major)
    uint32_t* __restrict__ hexch,     // [(smask+1)][64][512] f16-pair dwords
    int* __restrict__ flags,          // [256], monotone absolute t
    float* __restrict__ cstate,       // [64][1024] f32 persistent c
    int t0, int smask,
    const int* __restrict__ lengths,  // [64] or null
    float* __restrict__ dout) {       // [64][1024] f32 or null
    __shared__ f16 hbuf[16 * 1032];   // h_prev slice, padded stride
    __shared__ float xch[4 * 16 * 16];// cross-wave gate exchange
    int tid = threadIdx.x;
    int g = tid >> 6, lane = tid & 63;
    int lm = lane & 15, lq = lane >> 4;
    int bid = blockIdx.x;
    int bg = bid >> 6, jg = bid & 63;

    // W fragments resident in registers for all CH steps
    f16x8 wfrag[32];
    {
        int grow = g * 1024 + jg * 16 + lm;
        const f16* wp = Wh + (size_t)grow * 1024 + lq * 8;
#pragma unroll
        for (int kk = 0; kk < 32; kk++) wfrag[kk] = *(const f16x8*)(wp + kk * 32);
    }
    int eb = tid >> 4, eu = tid & 15;
    int batch = bg * 16 + eb;
    int hidx = jg * 16 + eu;
    float bias[4];
#pragma unroll
    for (int g2 = 0; g2 < 4; g2++) bias[g2] = bsum[g2 * 1024 + hidx];
    int mylen = (lengths != nullptr) ? lengths[batch] : -1;
    float c = (t0 > 0) ? cstate[(size_t)batch * 1024 + hidx] : 0.0f;
    const int myflag = bg * 64 + jg;

    for (int lt = 0; lt < CH; lt++) {
        int t = t0 + lt;
        // prefetch xp (recurrence-independent): latency hides under flag wait
        const f32x4 xpv = *(const f32x4*)(xp + ((size_t)lt * 64 + batch) * 4096 + (hidx << 2));
        f32x4 pre = f32x4{0.f, 0.f, 0.f, 0.f};
        if (t > 0) {
            if (tid < 64) {
                const int* fl = flags + bg * 64;
                for (;;) {
                    int v = __hip_atomic_load(fl + tid, __ATOMIC_RELAXED,
                                              __HIP_MEMORY_SCOPE_AGENT);
                    if (__all(v >= t)) break;
                    __builtin_amdgcn_s_sleep(1);
                }
            }
            __syncthreads();
            // stage h_{t-1} slice into LDS via device-coherent 64-bit loads
            const uint64_t* hp = (const uint64_t*)hexch
                + (size_t)((t - 1) & smask) * (NBATCH * 256);
#pragma unroll
            for (int i = 0; i < 16; i++) {
                int lin = tid + i * 256;          // [0,4096) 8B granules
                int b = lin >> 8, d = lin & 255;
                uint64_t v = __hip_atomic_load(
                    hp + (size_t)(bg * 16 + b) * 256 + d,
                    __ATOMIC_RELAXED, __HIP_MEMORY_SCOPE_AGENT);
                *(uint64_t*)((char*)hbuf + (size_t)b * 2064 + (size_t)d * 8) = v;
            }
            __syncthreads();
            f32x4 a0 = f32x4{0.f,0.f,0.f,0.f}, a1 = f32x4{0.f,0.f,0.f,0.f};
            f32x4 a2 = f32x4{0.f,0.f,0.f,0.f}, a3 = f32x4{0.f,0.f,0.f,0.f};
            const f16* hb = &hbuf[lm * 1032 + lq * 8];
#pragma unroll
            for (int kk = 0; kk < 32; kk += 4) {
                a0 = __builtin_amdgcn_mfma_f32_16x16x32_f16(*(const f16x8*)(hb + (kk + 0) * 32), wfrag[kk + 0], a0, 0, 0, 0);
                a1 = __builtin_amdgcn_mfma_f32_16x16x32_f16(*(const f16x8*)(hb + (kk + 1) * 32), wfrag[kk + 1], a1, 0, 0, 0);
                a2 = __builtin_amdgcn_mfma_f32_16x16x32_f16(*(const f16x8*)(hb + (kk + 2) * 32), wfrag[kk + 2], a2, 0, 0, 0);
                a3 = __builtin_amdgcn_mfma_f32_16x16x32_f16(*(const f16x8*)(hb + (kk + 3) * 32), wfrag[kk + 3], a3, 0, 0, 0);
            }
            pre = (a0 + a1) + (a2 + a3);
        }
        // cross-wave exchange: D element (m=lq*4+r = batch-in-group, n=lm = unit)
#pragma unroll
        for (int r = 0; r < 4; r++)
            xch[(g * 16 + lq * 4 + r) * 16 + lm] = pre[r];
        __syncthreads();
        float pg[4];
#pragma unroll
        for (int g2 = 0; g2 < 4; g2++)
            pg[g2] = xch[(g2 * 16 + eb) * 16 + eu] + xpv[g2] + bias[g2];
        float iv = sigmoidf_(pg[0]);
        float fv = sigmoidf_(pg[1]);
        float gv = tanh_(pg[2]);
        float ov = sigmoidf_(pg[3]);
        c = fv * c + iv * gv;
        float h = ov * tanh_(c);
        // publish h: pack f16 pair with neighbor lane, device-coherent store
        float hn = __shfl_xor(h, 1);
        if ((tid & 1) == 0) {
            uint16_t lo, hi;
            {
                f16 a = (f16)h, b2 = (f16)hn;
                lo = *(uint16_t*)&a; hi = *(uint16_t*)&b2;
            }
            uint32_t pk = (uint32_t)lo | ((uint32_t)hi << 16);
            __hip_atomic_store(
                hexch + (size_t)(t & smask) * (NBATCH * 512)
                      + (size_t)batch * 512 + (hidx >> 1),
                pk, __ATOMIC_RELAXED, __HIP_MEMORY_SCOPE_AGENT);
        }
        if (dout != nullptr && t == mylen - 1)
            dout[(size_t)batch * 1024 + hidx] = h;
        __syncthreads();  // drains vmcnt(0): all waves' h stores are at the MALL
        if (tid == 0)
            __hip_atomic_store(flags + myflag, t + 1, __ATOMIC_RELAXED,
                               __HIP_MEMORY_SCOPE_AGENT);
    }
    cstate[(size_t)batch * 1024 + hidx] = c;
}

extern "C" void kernel_launch(void* const* d_in, const int* in_sizes, int n_in,
                              void* d_out, int out_size, void* d_ws, size_t ws_size,
                              hipStream_t stream) {
    const int*   x     = (const int*)d_in[0];
    const int*   len   = (const int*)d_in[1];
    const float* emb   = (const float*)d_in[2];
    const float* W_ih0 = (const float*)d_in[3];
    const float* b_ih0 = (const float*)d_in[4];
    const float* A_ih0 = (const float*)d_in[5];
    const float* B_ih0 = (const float*)d_in[6];
    const float* W_hh0 = (const float*)d_in[7];
    const float* b_hh0 = (const float*)d_in[8];
    const float* A_hh0 = (const float*)d_in[9];
    const float* B_hh0 = (const float*)d_in[10];
    const float* W_ih1 = (const float*)d_in[11];
    const float* b_ih1 = (const float*)d_in[12];
    const float* A_ih1 = (const float*)d_in[13];
    const float* B_ih1 = (const float*)d_in[14];
    const float* W_hh1 = (const float*)d_in[15];
    const float* b_hh1 = (const float*)d_in[16];
    const float* A_hh1 = (const float*)d_in[17];
    const float* B_hh1 = (const float*)d_in[18];

    char* ws = (char*)d_ws;
    size_t off = 0;
    auto alloc = [&](size_t bytes) {
        size_t o = off;
        off += (bytes + 255) & ~(size_t)255;
        return o;
    };
    f16*   W0f    = (f16*)(ws + alloc((size_t)4096 * 512 * 2));
    f16*   Wh0f   = (f16*)(ws + alloc((size_t)4096 * 1024 * 2));
    f16*   W1f    = (f16*)(ws + alloc((size_t)4096 * 1024 * 2));
    f16*   Wh1f   = (f16*)(ws + alloc((size_t)4096 * 1024 * 2));
    float* bsum0  = (float*)(ws + alloc(4096 * 4));
    float* bsum1  = (float*)(ws + alloc(4096 * 4));
    int*   flags0 = (int*)(ws + alloc(4096));
    int*   flags1 = (int*)(ws + alloc(4096));
    float* c0st   = (float*)(ws + alloc((size_t)64 * 1024 * 4));
    float* c1st   = (float*)(ws + alloc((size_t)64 * 1024 * 4));
    f16*   hx1    = (f16*)(ws + alloc((size_t)2 * 64 * 1024 * 2));
    f16*   seqc   = (f16*)(ws + alloc((size_t)CH * 64 * 512 * 2));
    f16*   h0c    = (f16*)(ws + alloc((size_t)CH * 64 * 1024 * 2));
    float* xpc    = (float*)(ws + alloc((size_t)CH * 64 * 4096 * 4));
    (void)ws_size; (void)in_sizes; (void)n_in; (void)out_size;

    fold_lora<<<1024, 256, 0, stream>>>(W_ih0, B_ih0, A_ih0, W0f, 512);
    fold_lora<<<2048, 256, 0, stream>>>(W_hh0, B_hh0, A_hh0, Wh0f, 1024);
    fold_lora<<<2048, 256, 0, stream>>>(W_ih1, B_ih1, A_ih1, W1f, 1024);
    fold_lora<<<2048, 256, 0, stream>>>(W_hh1, B_hh1, A_hh1, Wh1f, 1024);
    init_misc<<<256, 256, 0, stream>>>(b_ih0, b_hh0, b_ih1, b_hh1,
                                       bsum0, bsum1, flags0, flags1, c0st, c1st);

    for (int cix = 0; cix < NCH; cix++) {
        int t0 = cix * CH;
        embed_gather<<<CH, 256, 0, stream>>>(x, emb, seqc, t0);
        gemm_nt<<<1024, 256, 0, stream>>>(seqc, W0f, xpc, 512);
        lstm_recur<<<256, 256, 0, stream>>>(xpc, Wh0f, bsum0, (uint32_t*)h0c,
                                            flags0, c0st, t0, CH - 1,
                                            nullptr, nullptr);
        gemm_nt<<<1024, 256, 0, stream>>>(h0c, W1f, xpc, 1024);
        lstm_recur<<<256, 256, 0, stream>>>(xpc, Wh1f, bsum1, (uint32_t*)hx1,
                                            flags1, c1st, t0, 1,
                                            len, (float*)d_out);
    }
}